// Round 7
// baseline (129.896 us; speedup 1.0000x reference)
//
#include <hip/hip_runtime.h>

typedef unsigned short u16;
typedef unsigned int u32;
typedef short v8s __attribute__((ext_vector_type(8)));
typedef float v4f __attribute__((ext_vector_type(4)));
typedef float v2f __attribute__((ext_vector_type(2)));

__device__ __forceinline__ float bflo(u32 d){union{u32 i;float f;}u;u.i=d<<16;return u.f;}
__device__ __forceinline__ float bfhi(u32 d){union{u32 i;float f;}u;u.i=d&0xffff0000u;return u.f;}
__device__ __forceinline__ u16 f2bfr(float f){union{float f;u32 i;}u;u.f=f;return (u16)((u.i+0x8000u)>>16);}
// (round(a) in lo16) | (round(b) in hi16): add, add, v_perm_b32
__device__ __forceinline__ u32 pk2bf(float a,float b){
    union{float f;u32 i;}ua,ub; ua.f=a; ub.f=b;
    u32 x = ua.i + 0x8000u, y = ub.i + 0x8000u;
    return __builtin_amdgcn_perm(y, x, 0x07060302);
}
__device__ __forceinline__ v8s pack8(const float* w){
    union { uint4 u; v8s v; } c;
    c.u.x = pk2bf(w[0],w[1]); c.u.y = pk2bf(w[2],w[3]);
    c.u.z = pk2bf(w[4],w[5]); c.u.w = pk2bf(w[6],w[7]);
    return c.v;
}

// Flash S@Wh, two 16-row strips per wave (rows 16wv+l15 and +64).
// w = adj * max(Ei*Ej, Fi*Fj)  ==  adj * exp(lrelu(ei+ej))   (exact identity)
// Inner loop in packed float2 (v_pk_*_f32).
__device__ __forceinline__ void flash_att(
    int wv, int l15, int q4,
    const float* __restrict__ ADJ,
    const float* __restrict__ sEi, const float* __restrict__ sFi,
    const float* __restrict__ sEj, const float* __restrict__ sFj,
    const u16* __restrict__ sWhT,
    v4f acc[2][4], float invD[2])
{
    const int r0 = 16*wv + l15, r1 = r0 + 64;
    const v2f Ei0 = {sEi[r0], sEi[r0]}, Fi0 = {sFi[r0], sFi[r0]};
    const v2f Ei1 = {sEi[r1], sEi[r1]}, Fi1 = {sFi[r1], sFi[r1]};
    v2f D0 = {0.f,0.f}, D1 = {0.f,0.f};
    #pragma unroll
    for (int s = 0; s < 2; ++s)
        #pragma unroll
        for (int ct = 0; ct < 4; ++ct) acc[s][ct] = (v4f){0.f,0.f,0.f,0.f};

    for (int ks = 0; ks < 4; ++ks) {
        const int ko = ks*32 + q4*8;
        const v2f* Ejp = (const v2f*)(sEj + ko);
        const v2f* Fjp = (const v2f*)(sFj + ko);
        const v2f* A0p = (const v2f*)(ADJ + r0*128 + ko);
        const v2f* A1p = (const v2f*)(ADJ + r1*128 + ko);
        union { u32 u[4]; v8s v; } P0, P1;
        #pragma unroll
        for (int p = 0; p < 4; ++p) {
            v2f E = Ejp[p], F = Fjp[p];
            v2f a0 = A0p[p], a1 = A1p[p];
            v2f m0 = __builtin_elementwise_max(Ei0*E, Fi0*F);
            v2f m1 = __builtin_elementwise_max(Ei1*E, Fi1*F);
            v2f x0 = m0 * a0;
            v2f x1 = m1 * a1;
            D0 += x0; D1 += x1;
            P0.u[p] = pk2bf(x0.x, x0.y);
            P1.u[p] = pk2bf(x1.x, x1.y);
        }
        #pragma unroll
        for (int ct = 0; ct < 4; ++ct) {
            v8s B = *(const v8s*)(sWhT + (16*ct + l15)*136 + ko);
            acc[0][ct] = __builtin_amdgcn_mfma_f32_16x16x32_bf16(P0.v, B, acc[0][ct], 0,0,0);
            acc[1][ct] = __builtin_amdgcn_mfma_f32_16x16x32_bf16(P1.v, B, acc[1][ct], 0,0,0);
        }
    }
    float d0 = D0.x + D0.y, d1 = D1.x + D1.y;
    d0 += __shfl_xor(d0, 16); d0 += __shfl_xor(d0, 32);
    d1 += __shfl_xor(d1, 16); d1 += __shfl_xor(d1, 32);
    invD[0] = 1.f / d0; invD[1] = 1.f / d1;
}

__global__ __launch_bounds__(256, 4) void graphmixer_kernel(
    const float* __restrict__ C,     // (1024,128)
    const float* __restrict__ ADJ,   // (128,128)
    const float* __restrict__ EMB,   // (128,8)
    const float* __restrict__ W1,    // (9,64)
    const float* __restrict__ A1,    // (128)
    const float* __restrict__ W2,    // (64,64)
    const float* __restrict__ A2,    // (128)
    const float* __restrict__ LN1G, const float* __restrict__ LN1B,
    const float* __restrict__ LN2G, const float* __restrict__ LN2B,
    const float* __restrict__ HGW,  const float* __restrict__ HGB,
    const float* __restrict__ MLP1W, const float* __restrict__ MLP1B,
    const float* __restrict__ MLP2W, const float* __restrict__ MLP2B,
    const float* __restrict__ HMW,  const float* __restrict__ HMB,
    const float* __restrict__ G1W,  const float* __restrict__ G1B,
    const float* __restrict__ G2W,  const float* __restrict__ G2B,
    float* __restrict__ OUT)
{
    const int b = blockIdx.x, t = threadIdx.x;
    const int lane = t & 63, wv = t >> 6;
    const int l15 = lane & 15, q4 = lane >> 4;

    __shared__ __align__(16) unsigned char smem[40096];
    u16*   sWhT = (u16*)(smem);            // [64][136] bf16 : Wh1T then Wh2T  (17408)
    u16*   sH1  = (u16*)(smem + 17408);    // [128][72] bf16                    (18432)
    float* sEi  = (float*)(smem + 35840);  // 128: exp(ei)
    float* sFi  = (float*)(smem + 36352);  // 128: exp(0.2 ei)
    float* sEj  = (float*)(smem + 36864);  // 128: exp(ej)
    float* sFj  = (float*)(smem + 37376);  // 128: exp(0.2 ej)
    float* colp = (float*)(smem + 37888);  // 256
    float* sScr = (float*)(smem + 38912);  // 136
    float* v2i  = (float*)(smem + 39456);  // 64
    float* v2j  = (float*)(smem + 39712);  // 64
    float* v1i  = (float*)(smem + 39968);  // 9 (pad 16)
    float* v1j  = (float*)(smem + 40032);  // 9 (pad 16)
    // aliases in the sH1 region (dead until P4 epilogue):
    float* sEmb = (float*)(smem + 17408);  // 1024 f32
    float* sC   = (float*)(smem + 21504);  // 128 f32

    const float* Cb = C + b*128;

    // ================= P0 =================
    if (wv == 0) {
        #pragma unroll
        for (int q = 0; q < 4; ++q)
            ((float4*)sEmb)[lane + 64*q] = ((const float4*)EMB)[lane + 64*q];
        if (lane < 32) ((float4*)sC)[lane] = ((const float4*)Cb)[lane];
        if (lane >= 32 && lane < 41) {            // v1i[f] = W1[f][:] . a1_i
            int f = lane - 32; float a = 0.f;
            for (int q = 0; q < 16; ++q) {
                float4 w = *(const float4*)(W1 + f*64 + q*4);
                float4 x = *(const float4*)(A1 + q*4);
                a += w.x*x.x + w.y*x.y + w.z*x.z + w.w*x.w;
            }
            v1i[f] = a;
        } else if (lane >= 48 && lane < 57) {     // v1j
            int f = lane - 48; float a = 0.f;
            for (int q = 0; q < 16; ++q) {
                float4 w = *(const float4*)(W1 + f*64 + q*4);
                float4 x = *(const float4*)(A1 + 64 + q*4);
                a += w.x*x.x + w.y*x.y + w.z*x.z + w.w*x.w;
            }
            v1j[f] = a;
        }
    } else if (wv == 3) {                         // v2i/v2j[k] = W2[k][:] . a2_{i,j}
        float ai = 0.f, aj = 0.f;
        for (int q = 0; q < 16; ++q) {
            float4 w  = *(const float4*)(W2 + lane*64 + q*4);
            float4 xi = *(const float4*)(A2 + q*4);
            float4 xj = *(const float4*)(A2 + 64 + q*4);
            ai += w.x*xi.x + w.y*xi.y + w.z*xi.z + w.w*xi.w;
            aj += w.x*xj.x + w.y*xj.y + w.z*xj.z + w.w*xj.w;
        }
        v2i[lane] = ai; v2j[lane] = aj;
    } else if (wv == 1) {                         // q_mlp head (wave-private)
        float a = 0.f;
        for (int k = 0; k < 128; k += 4) {
            float4 c4 = *(const float4*)(Cb + k);
            a += c4.x*MLP1W[k*64+lane] + c4.y*MLP1W[(k+1)*64+lane]
               + c4.z*MLP1W[(k+2)*64+lane] + c4.w*MLP1W[(k+3)*64+lane];
        }
        sScr[lane] = fmaxf(a + MLP1B[lane], 0.f);
        float a2 = 0.f;
        for (int k = 0; k < 64; ++k) a2 += sScr[k] * MLP2W[k*64 + lane];
        float x2 = fmaxf(a2 + MLP2B[lane], 0.f);
        float p1 = x2 * HMW[lane];
        #pragma unroll
        for (int off = 32; off >= 1; off >>= 1) p1 += __shfl_down(p1, off);
        if (lane == 0) sScr[128] = p1 + HMB[0];
    } else {                                      // wv==2: gate head (wave-private)
        float a = 0.f;
        for (int k = 0; k < 128; k += 4) {
            float4 c4 = *(const float4*)(Cb + k);
            a += c4.x*G1W[k*64+lane] + c4.y*G1W[(k+1)*64+lane]
               + c4.z*G1W[(k+2)*64+lane] + c4.w*G1W[(k+3)*64+lane];
        }
        float g1 = fmaxf(a + G1B[lane], 0.f);
        float p2 = g1 * G2W[lane];
        #pragma unroll
        for (int off = 32; off >= 1; off >>= 1) p2 += __shfl_down(p2, off);
        if (lane == 0) sScr[129] = 1.f / (1.f + __expf(-(p2 + G2B[0])));
    }
    __syncthreads();   // b1

    // ================= P1: Wh1T + e1 exp-vectors (split even/odd threads) =================
    {
        const int o = lane, cc = wv;
        float w1f[9];
        #pragma unroll
        for (int f = 0; f < 9; ++f) w1f[f] = W1[f*64 + o];
        float whv[32];
        for (int i = 0; i < 32; ++i) {
            const int ig = cc*32 + i;
            float a = sC[ig] * w1f[0];
            float4 e0 = *(const float4*)(sEmb + ig*8);
            float4 e1 = *(const float4*)(sEmb + ig*8 + 4);
            a += e0.x*w1f[1] + e0.y*w1f[2] + e0.z*w1f[3] + e0.w*w1f[4];
            a += e1.x*w1f[5] + e1.y*w1f[6] + e1.z*w1f[7] + e1.w*w1f[8];
            whv[i] = a;
        }
        u32 p[16];
        #pragma unroll
        for (int q = 0; q < 16; ++q) p[q] = pk2bf(whv[2*q], whv[2*q+1]);
        uint4* dst = (uint4*)(sWhT + o*136 + cc*32);
        dst[0] = ((uint4*)p)[0]; dst[1] = ((uint4*)p)[1];
        dst[2] = ((uint4*)p)[2]; dst[3] = ((uint4*)p)[3];
    }
    {
        // e1: thread t handles row t>>1; even threads -> ei, odd -> ej
        const int row = t >> 1;
        const float* vv = (t & 1) ? v1j : v1i;
        float c = sC[row];
        float4 e0 = *(const float4*)(sEmb + row*8);
        float4 e1 = *(const float4*)(sEmb + row*8 + 4);
        float e = c*vv[0] + e0.x*vv[1]+e0.y*vv[2]+e0.z*vv[3]+e0.w*vv[4]
                          + e1.x*vv[5]+e1.y*vv[6]+e1.z*vv[7]+e1.w*vv[8];
        if (t & 1) { sEj[row] = __expf(e); sFj[row] = __expf(0.2f*e); }
        else       { sEi[row] = __expf(e); sFi[row] = __expf(0.2f*e); }
    }
    __syncthreads();   // b2

    // ================= P4: flash S1@Wh1 + (1/D, ELU, LN1) -> sH1 =================
    {
        v4f acc[2][4]; float invD[2];
        flash_att(wv, l15, q4, ADJ, sEi, sFi, sEj, sFj, sWhT, acc, invD);

        float g4[4], b4[4];
        #pragma unroll
        for (int ct = 0; ct < 4; ++ct) { g4[ct] = LN1G[16*ct + l15]; b4[ct] = LN1B[16*ct + l15]; }
        #pragma unroll
        for (int s = 0; s < 2; ++s) {
            const int rbase = 16*(wv + 4*s) + 4*q4;
            #pragma unroll
            for (int reg = 0; reg < 4; ++reg) {
                const int row = rbase + reg;
                const float rd = __shfl(invD[s], 4*q4 + reg);
                float x[4], s1 = 0.f, s2 = 0.f;
                #pragma unroll
                for (int ct = 0; ct < 4; ++ct) {
                    float v = acc[s][ct][reg] * rd;
                    v = (v > 0.f) ? v : (__expf(v) - 1.f);      // ELU
                    x[ct] = v; s1 += v; s2 += v*v;
                }
                s1 += __shfl_xor(s1, 1); s2 += __shfl_xor(s2, 1);
                s1 += __shfl_xor(s1, 2); s2 += __shfl_xor(s2, 2);
                s1 += __shfl_xor(s1, 4); s2 += __shfl_xor(s2, 4);
                s1 += __shfl_xor(s1, 8); s2 += __shfl_xor(s2, 8);
                const float mean = s1 * (1.f/64.f);
                const float var  = s2 * (1.f/64.f) - mean*mean;
                const float rstd = rsqrtf(var + 1e-5f);
                #pragma unroll
                for (int ct = 0; ct < 4; ++ct) {
                    float h = (x[ct] - mean) * rstd * g4[ct] + b4[ct];
                    sH1[row*72 + 16*ct + l15] = f2bfr(h);
                }
            }
        }
    }
    __syncthreads();   // b4

    // ====== e2 exp-vectors (all 256 threads, half-row each) | P6: Wh2 = h1@W2 ======
    {
        const int row = t >> 1, hb = (t & 1) * 32;
        const u16* hrow = sH1 + row*72 + hb;
        float ei = 0.f, ej = 0.f;
        for (int q = 0; q < 8; ++q) {
            uint2 d = *(const uint2*)(hrow + q*4);
            float h0 = bflo(d.x), h1v = bfhi(d.x), h2 = bflo(d.y), h3 = bfhi(d.y);
            const int kb = hb + q*4;
            ei += h0*v2i[kb+0] + h1v*v2i[kb+1] + h2*v2i[kb+2] + h3*v2i[kb+3];
            ej += h0*v2j[kb+0] + h1v*v2j[kb+1] + h2*v2j[kb+2] + h3*v2j[kb+3];
        }
        ei += __shfl_xor(ei, 1);
        ej += __shfl_xor(ej, 1);
        if ((t & 1) == 0) {
            sEi[row] = __expf(ei); sFi[row] = __expf(0.2f*ei);
            sEj[row] = __expf(ej); sFj[row] = __expf(0.2f*ej);
        }
    }
    {
        v4f acc2[2][4];
        #pragma unroll
        for (int s = 0; s < 2; ++s)
            #pragma unroll
            for (int ct = 0; ct < 4; ++ct) acc2[s][ct] = (v4f){0.f,0.f,0.f,0.f};
        #pragma unroll
        for (int ks = 0; ks < 2; ++ks) {
            const int kb = ks*32 + q4*8;
            v8s Bf[4];
            #pragma unroll
            for (int ct = 0; ct < 4; ++ct) {
                const float* wp = W2 + kb*64 + 16*ct + l15;
                float w8[8];
                #pragma unroll
                for (int j = 0; j < 8; ++j) w8[j] = wp[j*64];
                Bf[ct] = pack8(w8);
            }
            #pragma unroll
            for (int s = 0; s < 2; ++s) {
                v8s A = *(const v8s*)(sH1 + (16*(wv+4*s) + l15)*72 + kb);
                #pragma unroll
                for (int ct = 0; ct < 4; ++ct)
                    acc2[s][ct] = __builtin_amdgcn_mfma_f32_16x16x32_bf16(A, Bf[ct], acc2[s][ct], 0,0,0);
            }
        }
        #pragma unroll
        for (int s = 0; s < 2; ++s) {
            const int rb = 16*(wv+4*s) + 4*q4;
            #pragma unroll
            for (int ct = 0; ct < 4; ++ct) {
                const int col = 16*ct + l15;
                uint2 p;
                p.x = pk2bf(acc2[s][ct][0], acc2[s][ct][1]);
                p.y = pk2bf(acc2[s][ct][2], acc2[s][ct][3]);
                *(uint2*)(sWhT + col*136 + rb) = p;
            }
        }
    }
    __syncthreads();   // b6

    // ================= P7: flash S2@Wh2 + (1/D, +h1 relu, LN2, colsum) =================
    {
        v4f acc[2][4]; float invD[2];
        flash_att(wv, l15, q4, ADJ, sEi, sFi, sEj, sFj, sWhT, acc, invD);

        float g4[4], b4[4], colsum[4];
        #pragma unroll
        for (int ct = 0; ct < 4; ++ct) {
            g4[ct] = LN2G[16*ct + l15]; b4[ct] = LN2B[16*ct + l15]; colsum[ct] = 0.f;
        }
        #pragma unroll
        for (int s = 0; s < 2; ++s) {
            const int rbase = 16*(wv + 4*s) + 4*q4;
            #pragma unroll
            for (int reg = 0; reg < 4; ++reg) {
                const int row = rbase + reg;
                const float rd = __shfl(invD[s], 4*q4 + reg);
                float x[4], s1 = 0.f, s2 = 0.f;
                #pragma unroll
                for (int ct = 0; ct < 4; ++ct) {
                    float h1v = bflo((u32)sH1[row*72 + 16*ct + l15]);
                    float v = fmaxf(acc[s][ct][reg] * rd + h1v, 0.f);
                    x[ct] = v; s1 += v; s2 += v*v;
                }
                s1 += __shfl_xor(s1, 1); s2 += __shfl_xor(s2, 1);
                s1 += __shfl_xor(s1, 2); s2 += __shfl_xor(s2, 2);
                s1 += __shfl_xor(s1, 4); s2 += __shfl_xor(s2, 4);
                s1 += __shfl_xor(s1, 8); s2 += __shfl_xor(s2, 8);
                const float mean = s1 * (1.f/64.f);
                const float var  = s2 * (1.f/64.f) - mean*mean;
                const float rstd = rsqrtf(var + 1e-5f);
                #pragma unroll
                for (int ct = 0; ct < 4; ++ct)
                    colsum[ct] += (x[ct] - mean) * rstd * g4[ct] + b4[ct];
            }
        }
        #pragma unroll
        for (int ct = 0; ct < 4; ++ct) {
            colsum[ct] += __shfl_xor(colsum[ct], 16);
            colsum[ct] += __shfl_xor(colsum[ct], 32);
        }
        if (lane < 16) {
            #pragma unroll
            for (int ct = 0; ct < 4; ++ct) colp[wv*64 + ct*16 + lane] = colsum[ct];
        }
    }
    __syncthreads();   // b8

    // ================= final combine (wave 0) =================
    if (wv == 0) {
        float s = colp[lane] + colp[64 + lane] + colp[128 + lane] + colp[192 + lane];
        float p = s * (1.f/128.f) * HGW[lane];
        #pragma unroll
        for (int off = 32; off >= 1; off >>= 1) p += __shfl_down(p, off);
        if (lane == 0) OUT[b] = sScr[128] + sScr[129] * (p + HGB[0]);
    }
}

extern "C" void kernel_launch(void* const* d_in, const int* in_sizes, int n_in,
                              void* d_out, int out_size, void* d_ws, size_t ws_size,
                              hipStream_t stream) {
    (void)n_in; (void)out_size; (void)d_ws; (void)ws_size;
    const float* C     = (const float*)d_in[0];
    const float* ADJ   = (const float*)d_in[1];
    const float* EMB   = (const float*)d_in[2];
    const float* W1    = (const float*)d_in[3];
    const float* A1    = (const float*)d_in[4];
    const float* W2    = (const float*)d_in[5];
    const float* A2    = (const float*)d_in[6];
    const float* LN1G  = (const float*)d_in[7];
    const float* LN1B  = (const float*)d_in[8];
    const float* LN2G  = (const float*)d_in[9];
    const float* LN2B  = (const float*)d_in[10];
    const float* HGW   = (const float*)d_in[11];
    const float* HGB   = (const float*)d_in[12];
    const float* MLP1W = (const float*)d_in[13];
    const float* MLP1B = (const float*)d_in[14];
    const float* MLP2W = (const float*)d_in[15];
    const float* MLP2B = (const float*)d_in[16];
    const float* HMW   = (const float*)d_in[17];
    const float* HMB   = (const float*)d_in[18];
    const float* G1W   = (const float*)d_in[19];
    const float* G1B   = (const float*)d_in[20];
    const float* G2W   = (const float*)d_in[21];
    const float* G2B   = (const float*)d_in[22];

    const int B = in_sizes[0] / 128;  // 1024

    graphmixer_kernel<<<dim3(B), dim3(256), 0, stream>>>(
        C, ADJ, EMB, W1, A1, W2, A2, LN1G, LN1B, LN2G, LN2B,
        HGW, HGB, MLP1W, MLP1B, MLP2W, MLP2B, HMW, HMB,
        G1W, G1B, G2W, G2B, (float*)d_out);
}